// Round 15
// baseline (134.893 us; speedup 1.0000x reference)
//
#include <hip/hip_runtime.h>

#define NV    10
#define DD    2048
#define TAPS  25
#define CHUNK 64              // channels per staged chunk
#define NCH   (DD / CHUNK)    // 32 chunks
#define NGRP  (DD / 64)       // 32 groups of 64 channels
#define OB    64

typedef __attribute__((address_space(1))) const unsigned int gu32;
typedef __attribute__((address_space(3))) unsigned int lu32;

__device__ __forceinline__ float bsign(float v) {
    return (v > 0.0f) ? 1.0f : ((v < 0.0f) ? -1.0f : 0.0f);
}

// Pack sign/nonzero bitmasks of values: one block per (n, 64-ch group).
// SEPARATE kernel (fusing into g costs ~25 us: R5-R9/R12 vs R3/R11/R13).
__global__ __launch_bounds__(64) void vpack_kernel(
        const float* __restrict__ values,
        unsigned long long* __restrict__ vnz,
        unsigned long long* __restrict__ vng) {
    const int b    = blockIdx.x;      // 0..319
    const int n    = b >> 5;
    const int g    = b & 31;
    const int lane = threadIdx.x;
    float f = values[n * DD + g * 64 + lane];
    unsigned long long nz = __ballot(f != 0.0f);
    unsigned long long ng = __ballot(f < 0.0f);
    if (lane == 0) {
        vnz[n * NGRP + g] = nz;
        vng[n * NGRP + g] = ng;
    }
}

// Stage one 64-channel chunk (1600 floats = 400 float4): wave wv owns f4 range
// [wv*100, wv*100+100) = 1 full instr + 1 36-lane instr -> EXACTLY 2 vmcnt
// ticks per wave per chunk (uniform counting; masked lanes don't write, R3/R4).
__device__ __forceinline__ void stage_chunk(const float* __restrict__ gsrc,
                                            float* lbase, int lane, int wv) {
    const int b4 = wv * 100;
    __builtin_amdgcn_global_load_lds((gu32*)(gsrc + 4 * (b4 + lane)),
                                     (lu32*)(lbase + 4 * b4), 16, 0, 0);
    if (lane < 36) {
        __builtin_amdgcn_global_load_lds((gu32*)(gsrc + 4 * (b4 + 64 + lane)),
                                         (lu32*)(lbase + 4 * (b4 + 64)), 16, 0, 0);
    }
}

// G[tap][n][o] = sum_c sign(values[n][c])*sign(w[o][c][tap]) via ballot+popcount.
// R15 = R14's math at the SAME 8 blocks/CU occupancy, but T3/T4 staging:
// double-buffered CHUNK=64 + counted s_waitcnt vmcnt(2) -- the HBM queue is
// NEVER drained inside the loop (single vmcnt(0) at the tail). 2 barriers/chunk.
__global__ __launch_bounds__(256) void g_kernel(
        const float* __restrict__ w,
        const unsigned long long* __restrict__ gvnz,
        const unsigned long long* __restrict__ gvng,
        float* __restrict__ G) {
    const int o    = blockIdx.x;
    const int t    = threadIdx.x;
    const int lane = t & 63;
    const int wv   = t >> 6;

    __shared__ float buf[2][1664];                   // 2 x 6.5 KB (64-f pad: quad overread)
    __shared__ unsigned long long s_wnz[2][TAPS];    // double-buffered chunk masks
    __shared__ unsigned long long s_wng[2][TAPS];
    __shared__ unsigned long long s_vnz[NV * NGRP];  // [n][g]
    __shared__ unsigned long long s_vng[NV * NGRP];

    const float* wo = w + (size_t)o * (DD * TAPS);

    // pack chunk in buf[bi] -> wmask[bi]: 7 tap-quad tasks, static unroll 2/wave.
    #define PACK_CHUNK(bi)                                                        \
    {                                                                             \
        const float* cbuf_ = buf[bi];                                             \
        _Pragma("unroll")                                                         \
        for (int i = 0; i < 2; ++i) {                                             \
            const int tk = wv + 4 * i;                                            \
            if (tk < 7) {                                                         \
                const int t0 = 4 * tk;                                            \
                const int ba = lane * TAPS + t0;                                  \
                float a0 = cbuf_[ba + 0];                                         \
                float a1 = cbuf_[ba + 1];                                         \
                float a2 = cbuf_[ba + 2];                                         \
                float a3 = cbuf_[ba + 3];                                         \
                unsigned long long z0 = __ballot(a0 != 0.0f);                     \
                unsigned long long g0 = __ballot(a0 <  0.0f);                     \
                unsigned long long z1 = __ballot(a1 != 0.0f);                     \
                unsigned long long g1 = __ballot(a1 <  0.0f);                     \
                unsigned long long z2 = __ballot(a2 != 0.0f);                     \
                unsigned long long g2 = __ballot(a2 <  0.0f);                     \
                unsigned long long z3 = __ballot(a3 != 0.0f);                     \
                unsigned long long g3 = __ballot(a3 <  0.0f);                     \
                if (lane == 0) {                                                  \
                    s_wnz[bi][t0] = z0;  s_wng[bi][t0] = g0;                      \
                    if (t0 + 1 < TAPS) {                                          \
                        s_wnz[bi][t0 + 1] = z1;  s_wng[bi][t0 + 1] = g1;          \
                        s_wnz[bi][t0 + 2] = z2;  s_wng[bi][t0 + 2] = g2;          \
                        s_wnz[bi][t0 + 3] = z3;  s_wng[bi][t0 + 3] = g3;          \
                    }                                                             \
                }                                                                 \
            }                                                                     \
        }                                                                         \
    }

    // ---- prologue: mask preload (drained), then chunks 0,1 into flight ----
    for (int e = t; e < NV * NGRP; e += 256) {       // 5 KB, L2-hot
        s_vnz[e] = gvnz[e];
        s_vng[e] = gvng[e];
    }
    asm volatile("s_waitcnt vmcnt(0) lgkmcnt(0)" ::: "memory");  // clean vmcnt baseline
    __builtin_amdgcn_sched_barrier(0);
    stage_chunk(wo,        buf[0], lane, wv);
    stage_chunk(wo + 1600, buf[1], lane, wv);
    asm volatile("s_waitcnt vmcnt(2)" ::: "memory"); // chunk 0 landed; chunk 1 in flight
    __builtin_amdgcn_sched_barrier(0);
    __builtin_amdgcn_s_barrier();                    // buf[0] ready for all; masks visible

    const int tap = t / NV;   // accum ownership: t<250 -> (tap, n)
    const int n   = t - tap * NV;
    int acc = 0;

    // ---- main loop: Phase A = pack(ch) || acc(ch-1); Phase B = stage(ch+2),
    //      counted vmcnt(2) [never 0], barrier. ----
    for (int ch = 0; ch < NCH; ++ch) {
        const int cb = ch & 1;
        PACK_CHUNK(cb)
        if (ch > 0 && t < NV * TAPS) {
            unsigned long long wnz = s_wnz[cb ^ 1][tap];
            unsigned long long wng = s_wng[cb ^ 1][tap];
            unsigned long long vz  = s_vnz[n * NGRP + (ch - 1)];
            unsigned long long vg  = s_vng[n * NGRP + (ch - 1)];
            unsigned long long nzb = wnz & vz;
            // exact: S += popc(bothnz) - 2*popc(signdiff & bothnz); zeros handled
            acc += (int)__popcll(nzb) - 2 * (int)__popcll((wng ^ vg) & nzb);
        }
        asm volatile("s_waitcnt lgkmcnt(0)" ::: "memory");
        __builtin_amdgcn_sched_barrier(0);
        __builtin_amdgcn_s_barrier();                // buf[cb] reads done; wmask[cb] published
        if (ch + 2 < NCH) {
            stage_chunk(wo + (size_t)(ch + 2) * 1600, buf[cb], lane, wv);
            asm volatile("s_waitcnt vmcnt(2)" ::: "memory");   // chunk ch+1 landed
        } else {
            asm volatile("s_waitcnt vmcnt(0)" ::: "memory");   // tail drain only
        }
        __builtin_amdgcn_sched_barrier(0);
        __builtin_amdgcn_s_barrier();                // buf[cb^1] = chunk ch+1 ready for all
    }
    // epilogue: accumulate last chunk
    if (t < NV * TAPS) {
        const int pb = (NCH - 1) & 1;
        unsigned long long wnz = s_wnz[pb][tap];
        unsigned long long wng = s_wng[pb][tap];
        unsigned long long vz  = s_vnz[n * NGRP + (NCH - 1)];
        unsigned long long vg  = s_vng[n * NGRP + (NCH - 1)];
        unsigned long long nzb = wnz & vz;
        acc += (int)__popcll(nzb) - 2 * (int)__popcll((wng ^ vg) & nzb);
    }
    #undef PACK_CHUNK

    if (t < NV * TAPS) {
        G[((size_t)(tap * NV + n) << 11) + o] = (float)acc;
    }
}

// ---- out_kernel: byte-identical to R11/R13/R14 (G-strip in LDS, +1-padded;
// lanes=positions; 25 hoisted row-offsets reused across 16 o's; bias added
// once after the exact integer sum -> bit-exact sign). ----
__global__ __launch_bounds__(256) void out_kernel(
        const float* __restrict__ x,
        const float* __restrict__ G,
        const float* __restrict__ bias,
        float* __restrict__ out) {
    const int b     = blockIdx.x >> 5;     // 16 batches
    const int oc    = blockIdx.x & 31;     // 32 o-strips
    const int obase = oc * OB;
    const int t     = threadIdx.x;
    const int lane  = t & 63;
    const int oq    = t >> 6;              // 0..3: o residue class per wave

    __shared__ float s_G[TAPS * NV * 65];  // [tap*10+n][65]: +1 pad -> nn spreads banks
    __shared__ int   s_idx[28 * 28];
    __shared__ float s_bias[OB];

    // stage G strip: 250 rows x 64 floats (16 float4 each)
    for (int e = t; e < TAPS * NV * 16; e += 256) {
        const int r  = e >> 4;
        const int li = (e & 15) << 2;
        const float4 v = *(const float4*)(G + ((size_t)r << 11) + obase + li);
        s_G[r * 65 + li]     = v.x;
        s_G[r * 65 + li + 1] = v.y;
        s_G[r * 65 + li + 2] = v.z;
        s_G[r * 65 + li + 3] = v.w;
    }
    for (int e = t; e < 28 * 28; e += 256) {
        s_idx[e] = (int)(x[b * 784 + e] * 9.0f);   // trunc, matches .astype(int32)
    }
    if (t < OB) s_bias[t] = bias[obase + t];
    __syncthreads();

    for (int grp = 0; grp < 3; ++grp) {
        const int pos = grp * 64 + lane;
        if (pos < 144) {
            const int oh = pos / 12;
            const int ow = pos - oh * 12;
            int rr[25];                              // static-indexed (fully unrolled)
            #pragma unroll
            for (int kh = 0; kh < 5; ++kh) {
                const int row = (oh * 2 + kh) * 28 + ow * 2;
                #pragma unroll
                for (int kw = 0; kw < 5; ++kw) {
                    const int nn = s_idx[row + kw];          // per-lane index
                    rr[kh * 5 + kw] = (kh * 5 + kw) * 650 + nn * 65;
                }
            }
            for (int ol = oq; ol < OB; ol += 4) {    // 16 o's reuse the 25 offsets
                float acc = 0.0f;                    // integer-exact accumulation
                #pragma unroll
                for (int tp = 0; tp < TAPS; ++tp) {
                    acc += s_G[rr[tp] + ol];         // 10 banks + broadcast: conflict-free
                }
                // bias added once after exact int sum -> bit-exact sign
                out[((size_t)(b * DD + obase + ol)) * 144 + pos] = bsign(acc + s_bias[ol]);
            }
        }
    }
}

extern "C" void kernel_launch(void* const* d_in, const int* in_sizes, int n_in,
                              void* d_out, int out_size, void* d_ws, size_t ws_size,
                              hipStream_t stream) {
    const float* x      = (const float*)d_in[0];   // [16,1,28,28]
    const float* values = (const float*)d_in[1];   // [10,2048]
    const float* w      = (const float*)d_in[2];   // [2048,2048,5,5] OIHW
    const float* bias   = (const float*)d_in[3];   // [2048]
    float* out = (float*)d_out;                    // [16,2048,12,12]

    unsigned long long* vnz = (unsigned long long*)d_ws;          // 2560 B
    unsigned long long* vng = vnz + NV * NGRP;                    // 2560 B
    float* G = (float*)((char*)d_ws + 8192);                      // 2 MB

    hipLaunchKernelGGL(vpack_kernel, dim3(NV * NGRP), dim3(64), 0, stream, values, vnz, vng);
    hipLaunchKernelGGL(g_kernel, dim3(DD), dim3(256), 0, stream, w, vnz, vng, G);
    hipLaunchKernelGGL(out_kernel, dim3(16 * (DD / OB)), dim3(256), 0, stream, x, G, bias, out);
}

// Round 16
// 117.237 us; speedup vs baseline: 1.1506x; 1.1506x over previous
//
#include <hip/hip_runtime.h>

#define NV    10
#define DD    2048
#define TAPS  25
#define CHUNK 128             // channels per staging chunk
#define NCHH  8               // chunks per HALF (1024 channels)
#define NGRP  (DD / 64)       // 32 groups of 64 channels
#define HGRP  16              // groups per half
#define OB    64

typedef __attribute__((address_space(1))) const unsigned int gu32;
typedef __attribute__((address_space(3))) unsigned int lu32;

__device__ __forceinline__ float bsign(float v) {
    return (v > 0.0f) ? 1.0f : ((v < 0.0f) ? -1.0f : 0.0f);
}

// Pack sign/nonzero bitmasks of values: one block per (n, 64-ch group).
// SEPARATE kernel (fusing into g costs ~25 us: R5-R9/R12 vs R3/R11/R13).
__global__ __launch_bounds__(64) void vpack_kernel(
        const float* __restrict__ values,
        unsigned long long* __restrict__ vnz,
        unsigned long long* __restrict__ vng) {
    const int b    = blockIdx.x;      // 0..319
    const int n    = b >> 5;
    const int g    = b & 31;
    const int lane = threadIdx.x;
    float f = values[n * DD + g * 64 + lane];
    unsigned long long nz = __ballot(f != 0.0f);
    unsigned long long ng = __ballot(f < 0.0f);
    if (lane == 0) {
        vnz[n * NGRP + g] = nz;
        vng[n * NGRP + g] = ng;
    }
}

// G2[half][tap][n][o] = sum over this half's 1024 channels (exact int in f32).
// R16 = R14's g (same pack-quads, 2 barriers/chunk, 8 blocks/CU) but HALF-K:
// grid 4096 = 2 all-resident cohorts -> second cohort starts block-by-block as
// the first retires, breaking the all-resident phase convoy that pins HBM at
// ~70% duty in R14 (2048 blocks = exactly resident capacity, phases lock).
__global__ __launch_bounds__(256) void g_kernel(
        const float* __restrict__ w,
        const unsigned long long* __restrict__ gvnz,
        const unsigned long long* __restrict__ gvng,
        float* __restrict__ G) {
    const int bid  = blockIdx.x;
    const int o    = bid >> 1;
    const int half = bid & 1;
    const int t    = threadIdx.x;
    const int lane = t & 63;
    const int wv   = t >> 6;

    __shared__ float ls_raw[CHUNK * TAPS + 32];          // 3200 floats, linear
    __shared__ unsigned long long s_wnz[2][TAPS * 2];    // double-buffered chunk masks
    __shared__ unsigned long long s_wng[2][TAPS * 2];
    __shared__ unsigned long long s_vnz[NV * HGRP];      // this half's value masks [n][gl]
    __shared__ unsigned long long s_vng[NV * HGRP];

    const float* wo = w + (size_t)o * (DD * TAPS) + (size_t)half * (1024 * TAPS);

    // pack chunk in ls_raw -> mask buffer bi: 14 tasks = 7 tap-quads x 2 subgroups.
    // Static unroll 4/wave; quad overread at tap 24 is in-bounds (pad) and discarded.
    #define PACK_CHUNK(bi)                                                        \
    {                                                                             \
        _Pragma("unroll")                                                         \
        for (int i = 0; i < 4; ++i) {                                             \
            const int tk = wv + 4 * i;                                            \
            if (tk < 14) {                                                        \
                const int q  = tk >> 1;                                           \
                const int sb = tk & 1;                                            \
                const int t0 = 4 * q;                                             \
                const int ba = (sb * 64 + lane) * TAPS + t0;                      \
                float a0 = ls_raw[ba + 0];                                        \
                float a1 = ls_raw[ba + 1];                                        \
                float a2 = ls_raw[ba + 2];                                        \
                float a3 = ls_raw[ba + 3];                                        \
                unsigned long long z0 = __ballot(a0 != 0.0f);                     \
                unsigned long long g0 = __ballot(a0 <  0.0f);                     \
                unsigned long long z1 = __ballot(a1 != 0.0f);                     \
                unsigned long long g1 = __ballot(a1 <  0.0f);                     \
                unsigned long long z2 = __ballot(a2 != 0.0f);                     \
                unsigned long long g2 = __ballot(a2 <  0.0f);                     \
                unsigned long long z3 = __ballot(a3 != 0.0f);                     \
                unsigned long long g3 = __ballot(a3 <  0.0f);                     \
                if (lane == 0) {                                                  \
                    s_wnz[bi][(t0 + 0) * 2 + sb] = z0;                            \
                    s_wng[bi][(t0 + 0) * 2 + sb] = g0;                            \
                    if (t0 + 1 < TAPS) {                                          \
                        s_wnz[bi][(t0 + 1) * 2 + sb] = z1;                        \
                        s_wng[bi][(t0 + 1) * 2 + sb] = g1;                        \
                        s_wnz[bi][(t0 + 2) * 2 + sb] = z2;                        \
                        s_wng[bi][(t0 + 2) * 2 + sb] = g2;                        \
                        s_wnz[bi][(t0 + 3) * 2 + sb] = z3;                        \
                        s_wng[bi][(t0 + 3) * 2 + sb] = g3;                        \
                    }                                                             \
                }                                                                 \
            }                                                                     \
        }                                                                         \
    }

    // ---- prologue: chunk 0 into flight, then this half's mask preload (2.5 KB) ----
    for (int e = t; e < (CHUNK * TAPS) / 4; e += 256) {
        __builtin_amdgcn_global_load_lds((gu32*)(wo + 4 * e),
                                         (lu32*)(ls_raw + 4 * (e - lane)), 16, 0, 0);
    }
    if (t < NV * HGRP) {                                 // 160 threads, L2-hot
        const int n  = t >> 4;
        const int gl = t & 15;
        s_vnz[t] = gvnz[n * NGRP + half * HGRP + gl];
        s_vng[t] = gvng[n * NGRP + half * HGRP + gl];
    }
    __syncthreads();          // drains vmcnt: chunk 0 staged; value masks visible
    PACK_CHUNK(0)
    __syncthreads();          // pack(0) visible; ls_raw free for chunk 1

    const int tap = t / NV;   // accum ownership: t<250 -> (tap, n)
    const int n   = t - tap * NV;
    int acc = 0;

    // ---- main loop: per iter = stage(ch) || accumulate(ch-1), drain, pack(ch) ----
    for (int ch = 1; ch <= NCHH; ++ch) {
        if (ch < NCHH) {
            const float* src = wo + (size_t)(ch * CHUNK) * TAPS;
            for (int e = t; e < (CHUNK * TAPS) / 4; e += 256) {
                __builtin_amdgcn_global_load_lds((gu32*)(src + 4 * e),
                                                 (lu32*)(ls_raw + 4 * (e - lane)), 16, 0, 0);
            }
        }
        // accumulate chunk ch-1 in the staging-latency shadow (reads masks only)
        if (t < NV * TAPS) {
            const int pb = (ch - 1) & 1;
            #pragma unroll
            for (int sub = 0; sub < 2; ++sub) {
                unsigned long long wnz = s_wnz[pb][tap * 2 + sub];
                unsigned long long wng = s_wng[pb][tap * 2 + sub];
                unsigned long long vz  = s_vnz[n * HGRP + (ch - 1) * 2 + sub];
                unsigned long long vg  = s_vng[n * HGRP + (ch - 1) * 2 + sub];
                unsigned long long nzb = wnz & vz;
                // exact: S += popc(bothnz) - 2*popc(signdiff & bothnz); zeros handled
                acc += (int)__popcll(nzb) - 2 * (int)__popcll((wng ^ vg) & nzb);
            }
        }
        if (ch < NCHH) {
            __syncthreads();      // vmcnt drain: ls_raw = chunk ch
            PACK_CHUNK(ch & 1)
            __syncthreads();      // pack(ch) visible before acc(ch) / stage(ch+1)
        }
    }
    #undef PACK_CHUNK

    if (t < NV * TAPS) {
        // G2[half][tap*10+n][o]; each half-sum is an exact integer, |.| <= 25600
        G[((size_t)(half * (TAPS * NV) + tap * NV + n) << 11) + o] = (float)acc;
    }
}

// ---- out_kernel: R14's structure; stages A-half + B-half SUMMED into s_G
// (exact int add), then identical gather. Bias added once -> bit-exact sign. ----
__global__ __launch_bounds__(256) void out_kernel(
        const float* __restrict__ x,
        const float* __restrict__ G,
        const float* __restrict__ bias,
        float* __restrict__ out) {
    const int b     = blockIdx.x >> 5;     // 16 batches
    const int oc    = blockIdx.x & 31;     // 32 o-strips
    const int obase = oc * OB;
    const int t     = threadIdx.x;
    const int lane  = t & 63;
    const int oq    = t >> 6;              // 0..3: o residue class per wave

    __shared__ float s_G[TAPS * NV * 65];  // [tap*10+n][65]: +1 pad -> nn spreads banks
    __shared__ int   s_idx[28 * 28];
    __shared__ float s_bias[OB];

    // stage G strip: 250 rows x 64 floats; sum the two K-halves (exact ints)
    for (int e = t; e < TAPS * NV * 16; e += 256) {
        const int r  = e >> 4;
        const int li = (e & 15) << 2;
        const float4 va = *(const float4*)(G + ((size_t)r << 11) + obase + li);
        const float4 vb = *(const float4*)(G + ((size_t)(r + TAPS * NV) << 11) + obase + li);
        s_G[r * 65 + li]     = va.x + vb.x;
        s_G[r * 65 + li + 1] = va.y + vb.y;
        s_G[r * 65 + li + 2] = va.z + vb.z;
        s_G[r * 65 + li + 3] = va.w + vb.w;
    }
    for (int e = t; e < 28 * 28; e += 256) {
        s_idx[e] = (int)(x[b * 784 + e] * 9.0f);   // trunc, matches .astype(int32)
    }
    if (t < OB) s_bias[t] = bias[obase + t];
    __syncthreads();

    for (int grp = 0; grp < 3; ++grp) {
        const int pos = grp * 64 + lane;
        if (pos < 144) {
            const int oh = pos / 12;
            const int ow = pos - oh * 12;
            int rr[25];                              // static-indexed (fully unrolled)
            #pragma unroll
            for (int kh = 0; kh < 5; ++kh) {
                const int row = (oh * 2 + kh) * 28 + ow * 2;
                #pragma unroll
                for (int kw = 0; kw < 5; ++kw) {
                    const int nn = s_idx[row + kw];          // per-lane index
                    rr[kh * 5 + kw] = (kh * 5 + kw) * 650 + nn * 65;
                }
            }
            for (int ol = oq; ol < OB; ol += 4) {    // 16 o's reuse the 25 offsets
                float acc = 0.0f;                    // integer-exact accumulation
                #pragma unroll
                for (int tp = 0; tp < TAPS; ++tp) {
                    acc += s_G[rr[tp] + ol];         // 10 banks + broadcast: conflict-free
                }
                // bias added once after exact int sum -> bit-exact sign
                out[((size_t)(b * DD + obase + ol)) * 144 + pos] = bsign(acc + s_bias[ol]);
            }
        }
    }
}

extern "C" void kernel_launch(void* const* d_in, const int* in_sizes, int n_in,
                              void* d_out, int out_size, void* d_ws, size_t ws_size,
                              hipStream_t stream) {
    const float* x      = (const float*)d_in[0];   // [16,1,28,28]
    const float* values = (const float*)d_in[1];   // [10,2048]
    const float* w      = (const float*)d_in[2];   // [2048,2048,5,5] OIHW
    const float* bias   = (const float*)d_in[3];   // [2048]
    float* out = (float*)d_out;                    // [16,2048,12,12]

    unsigned long long* vnz = (unsigned long long*)d_ws;          // 2560 B
    unsigned long long* vng = vnz + NV * NGRP;                    // 2560 B
    float* G = (float*)((char*)d_ws + 8192);                      // 2 x 2 MB halves

    hipLaunchKernelGGL(vpack_kernel, dim3(NV * NGRP), dim3(64), 0, stream, values, vnz, vng);
    hipLaunchKernelGGL(g_kernel, dim3(2 * DD), dim3(256), 0, stream, w, vnz, vng, G);
    hipLaunchKernelGGL(out_kernel, dim3(16 * (DD / OB)), dim3(256), 0, stream, x, G, bias, out);
}